// Round 1
// baseline (426.874 us; speedup 1.0000x reference)
//
#include <hip/hip_runtime.h>
#include <hip/hip_bf16.h>

// Problem constants
#define BATCH 32
#define LTOT 4096
#define CCH 64
#define NFFT 16
#define HOP 4
#define NF 9            // n_fft/2+1
#define T_FR 1025       // 1 + L/HOP
#define T_ROWS 1032     // padded rows in mag workspace (rows >= 1025 zeroed)
#define ICH 576         // C * NF
#define OCH 512
#define TY 1023         // conv output length
#define OUTW 128

typedef __attribute__((ext_vector_type(8))) _Float16 half8;
typedef __attribute__((ext_vector_type(4))) float floatx4;

// ---------------------------------------------------------------------------
// Kernel 1: STFT magnitude.  x [B, L, C] fp32 -> m_ws [b][t][c*9+f] fp16.
// Direct 16-point DFT with LDS cos/sin tables. Rows t in [1025, T_ROWS) zeroed.
// block = 256 threads = 64 c x 4 t; grid = (T_ROWS/4, B)
// ---------------------------------------------------------------------------
__global__ __launch_bounds__(256) void stft_kernel(const float* __restrict__ x,
                                                   _Float16* __restrict__ m_ws) {
  const int b = blockIdx.y;
  const int t0 = blockIdx.x * 4;
  const int tid = threadIdx.x;

  __shared__ float xs[28 * 64];    // frames for 4 t values: 4*4+12 = 28 rows of x
  __shared__ float ct[9 * 16], st[9 * 16];

  if (tid < 144) {
    int f = tid / 16, j = tid % 16;
    float ang = 3.14159265358979323846f * (float)(f * j) / 8.0f;
    ct[tid] = cosf(ang);
    st[tid] = sinf(ang);
  }

  // stage x rows l0 .. l0+27 with reflect padding
  const int l0 = t0 * HOP - 8;
  const float* xb = x + (size_t)b * LTOT * CCH;
  for (int it = 0; it < 7; ++it) {
    int e = it * 256 + tid;
    int r = e >> 6, c = e & 63;
    int l = l0 + r;
    if (l < 0) l = -l;
    if (l >= LTOT) l = 2 * LTOT - 2 - l;
    xs[r * 64 + c] = xb[(size_t)l * CCH + c];
  }
  __syncthreads();

  const int c = tid & 63, tq = tid >> 6;
  const int t = t0 + tq;
  if (t >= T_ROWS) return;
  _Float16* out = m_ws + ((size_t)b * T_ROWS + t) * ICH + c * NF;
  if (t >= T_FR) {
    for (int f = 0; f < NF; ++f) out[f] = (_Float16)0.0f;
    return;
  }
  float wx[16];
#pragma unroll
  for (int j = 0; j < 16; ++j) {
    // periodic hann: 0.5*(1 - cos(pi*j/8)) == 0.5*(1 - ct[16 + j])
    wx[j] = xs[(tq * 4 + j) * 64 + c] * (0.5f * (1.0f - ct[16 + j]));
  }
#pragma unroll
  for (int f = 0; f < NF; ++f) {
    float re = 0.0f, im = 0.0f;
#pragma unroll
    for (int j = 0; j < 16; ++j) {
      re += wx[j] * ct[f * 16 + j];
      im -= wx[j] * st[f * 16 + j];
    }
    out[f] = (_Float16)sqrtf(re * re + im * im);
  }
}

// ---------------------------------------------------------------------------
// Kernel 2: weight repack fp32 [O=512][I=576][K=3] -> fp16 wk[k][o][i]
// ---------------------------------------------------------------------------
__global__ __launch_bounds__(256) void wrepack_kernel(const float* __restrict__ w,
                                                      _Float16* __restrict__ wk) {
  int idx = blockIdx.x * 256 + threadIdx.x;   // o*576 + i
  if (idx >= OCH * ICH) return;
  int o = idx / ICH, i = idx - o * ICH;
  const float* src = w + (size_t)o * (ICH * 3) + i * 3;
#pragma unroll
  for (int k = 0; k < 3; ++k)
    wk[(size_t)k * OCH * ICH + idx] = (_Float16)src[k];
}

// ---------------------------------------------------------------------------
// Kernel 3: conv-as-GEMM.  For each batch b:
//   y[o][t] = sum_{k=0..2} sum_i wk[k][o][i] * m[b][t+k][i]
// 128x128 tile, BK=64 (each K-block has uniform tap k since 576%64==0 -> free
// im2col: B-tile base row shifts by k). 4 waves, each 64x64 via 4x4 mfma 16x16x32.
// grid = (8 t-tiles, 4 o-tiles, 32 batches), block 256.
// ---------------------------------------------------------------------------
#define BM 128
#define BN 128
#define BK 64
#define LDK 72   // LDS row stride in halves: +16B pad -> 2-way bank alias (free)

__global__ __launch_bounds__(256, 2) void conv_gemm_kernel(
    const _Float16* __restrict__ m_ws, const _Float16* __restrict__ wk,
    float* __restrict__ y) {
  const int b = blockIdx.z;
  const int o0 = blockIdx.y * BM;
  const int t0 = blockIdx.x * BN;
  const int tid = threadIdx.x;
  const int wave = tid >> 6, lane = tid & 63;
  const int wm = wave >> 1, wn = wave & 1;       // 2x2 wave grid

  __shared__ _Float16 as[BM * LDK];
  __shared__ _Float16 bs[BN * LDK];

  floatx4 acc[4][4];
#pragma unroll
  for (int mt = 0; mt < 4; ++mt)
#pragma unroll
    for (int nt = 0; nt < 4; ++nt)
      acc[mt][nt] = (floatx4)0.0f;

  const _Float16* mb = m_ws + (size_t)b * T_ROWS * ICH;
  const int frow = lane & 15;          // non-K fragment index
  const int kq = (lane >> 4) * 8;      // K sub-offset per quad

  for (int kb = 0; kb < 27; ++kb) {
    const int ksh = kb / 9;                    // conv tap 0..2
    const int i0 = (kb - ksh * 9) * BK;        // (kb%9)*64
    const _Float16* ag = wk + (size_t)ksh * OCH * ICH + (size_t)o0 * ICH + i0;
    const _Float16* bg = mb + (size_t)(t0 + ksh) * ICH + i0;

#pragma unroll
    for (int it = 0; it < 4; ++it) {
      int e = it * 256 + tid;                  // 0..1023 chunk id
      int row = e >> 3, c8 = (e & 7) * 8;
      *(half8*)(&as[row * LDK + c8]) = *(const half8*)(ag + (size_t)row * ICH + c8);
      *(half8*)(&bs[row * LDK + c8]) = *(const half8*)(bg + (size_t)row * ICH + c8);
    }
    __syncthreads();

#pragma unroll
    for (int kk = 0; kk < BK; kk += 32) {
      half8 af[4], bf[4];
#pragma unroll
      for (int mt = 0; mt < 4; ++mt)
        af[mt] = *(const half8*)(&as[(wm * 64 + mt * 16 + frow) * LDK + kk + kq]);
#pragma unroll
      for (int nt = 0; nt < 4; ++nt)
        bf[nt] = *(const half8*)(&bs[(wn * 64 + nt * 16 + frow) * LDK + kk + kq]);
#pragma unroll
      for (int mt = 0; mt < 4; ++mt)
#pragma unroll
        for (int nt = 0; nt < 4; ++nt)
          acc[mt][nt] = __builtin_amdgcn_mfma_f32_16x16x32_f16(af[mt], bf[nt],
                                                               acc[mt][nt], 0, 0, 0);
    }
    __syncthreads();
  }

  // epilogue: y[b][o][t], t stride padded to 1024
  const int col = lane & 15, quad = lane >> 4;
#pragma unroll
  for (int mt = 0; mt < 4; ++mt) {
#pragma unroll
    for (int nt = 0; nt < 4; ++nt) {
      int t = t0 + wn * 64 + nt * 16 + col;
      if (t >= TY) continue;
#pragma unroll
      for (int r = 0; r < 4; ++r) {
        int o = o0 + wm * 64 + mt * 16 + quad * 4 + r;
        y[(((size_t)b * OCH + o) << 10) + t] = acc[mt][nt][r];
      }
    }
  }
}

// ---------------------------------------------------------------------------
// Kernel 4: adaptive avg pool (overlapping torch bins) + bias.
// out[b][w][o] = bias[o] + mean_{t in [floor(w*1023/128), ceil((w+1)*1023/128))} y[b][o][t]
// grid = (128 w, 32 b), block = 512 (o)
// ---------------------------------------------------------------------------
__global__ __launch_bounds__(512) void pool_kernel(const float* __restrict__ y,
                                                   const float* __restrict__ bias,
                                                   float* __restrict__ out) {
  const int b = blockIdx.y, w = blockIdx.x;
  const int o = threadIdx.x;
  const int start = (w * TY) >> 7;
  const int end = ((w + 1) * TY + 127) >> 7;
  const float* yr = y + (((size_t)b * OCH + o) << 10);
  float s = 0.0f;
  for (int t = start; t < end; ++t) s += yr[t];
  out[((size_t)b * OUTW + w) * OCH + o] = s / (float)(end - start) + bias[o];
}

// ---------------------------------------------------------------------------
extern "C" void kernel_launch(void* const* d_in, const int* in_sizes, int n_in,
                              void* d_out, int out_size, void* d_ws, size_t ws_size,
                              hipStream_t stream) {
  const float* x = (const float*)d_in[0];       // [32, 4096, 64]
  const float* weight = (const float*)d_in[1];  // [512, 576, 3]
  const float* bias = (const float*)d_in[2];    // [512]
  float* out = (float*)d_out;                   // [32, 128, 512]

  char* ws = (char*)d_ws;
  const size_t m_bytes = (size_t)BATCH * T_ROWS * ICH * sizeof(_Float16);  // 38,043,648
  const size_t w_bytes = (size_t)3 * OCH * ICH * sizeof(_Float16);         // 1,769,472
  _Float16* m_ws = (_Float16*)ws;
  _Float16* wk = (_Float16*)(ws + m_bytes);
  float* y = (float*)(ws + m_bytes + w_bytes);  // [32][512][1024] fp32 = 67,108,864

  hipLaunchKernelGGL(stft_kernel, dim3(T_ROWS / 4, BATCH), dim3(256), 0, stream,
                     x, m_ws);
  hipLaunchKernelGGL(wrepack_kernel, dim3((OCH * ICH + 255) / 256), dim3(256), 0,
                     stream, weight, wk);
  hipLaunchKernelGGL(conv_gemm_kernel, dim3(8, 4, BATCH), dim3(256), 0, stream,
                     m_ws, wk, y);
  hipLaunchKernelGGL(pool_kernel, dim3(OUTW, BATCH), dim3(512), 0, stream,
                     y, bias, out);
}

// Round 2
// 213.634 us; speedup vs baseline: 1.9982x; 1.9982x over previous
//
#include <hip/hip_runtime.h>
#include <hip/hip_bf16.h>

// Problem constants
#define BATCH 32
#define LTOT 4096
#define CCH 64
#define NFFT 16
#define HOP 4
#define NF 9            // n_fft/2+1
#define T_FR 1025       // 1 + L/HOP
#define T_ROWS 1032     // padded rows in mag workspace (rows >= 1025 zeroed)
#define ICH 576         // C * NF
#define OCH 512
#define TY 1023         // conv output length
#define OUTW 128

typedef __attribute__((ext_vector_type(8))) _Float16 half8;
typedef __attribute__((ext_vector_type(4))) float floatx4;

// ---------------------------------------------------------------------------
// Kernel 1: STFT magnitude.  x [B, L, C] fp32 -> m_ws [b][t][c*9+f] fp16.
// Direct 16-point DFT with LDS cos/sin tables. Rows t in [1025, T_ROWS) zeroed.
// block = 256 threads = 64 c x 4 t; grid = (T_ROWS/4, B)
// ---------------------------------------------------------------------------
__global__ __launch_bounds__(256) void stft_kernel(const float* __restrict__ x,
                                                   _Float16* __restrict__ m_ws) {
  const int b = blockIdx.y;
  const int t0 = blockIdx.x * 4;
  const int tid = threadIdx.x;

  __shared__ float xs[28 * 64];    // frames for 4 t values: 4*4+12 = 28 rows of x
  __shared__ float ct[9 * 16], st[9 * 16];

  if (tid < 144) {
    int f = tid / 16, j = tid % 16;
    float ang = 3.14159265358979323846f * (float)(f * j) / 8.0f;
    ct[tid] = cosf(ang);
    st[tid] = sinf(ang);
  }

  // stage x rows l0 .. l0+27 with reflect padding
  const int l0 = t0 * HOP - 8;
  const float* xb = x + (size_t)b * LTOT * CCH;
  for (int it = 0; it < 7; ++it) {
    int e = it * 256 + tid;
    int r = e >> 6, c = e & 63;
    int l = l0 + r;
    if (l < 0) l = -l;
    if (l >= LTOT) l = 2 * LTOT - 2 - l;
    xs[r * 64 + c] = xb[(size_t)l * CCH + c];
  }
  __syncthreads();

  const int c = tid & 63, tq = tid >> 6;
  const int t = t0 + tq;
  if (t >= T_ROWS) return;
  _Float16* out = m_ws + ((size_t)b * T_ROWS + t) * ICH + c * NF;
  if (t >= T_FR) {
    for (int f = 0; f < NF; ++f) out[f] = (_Float16)0.0f;
    return;
  }
  float wx[16];
#pragma unroll
  for (int j = 0; j < 16; ++j) {
    // periodic hann: 0.5*(1 - cos(pi*j/8)) == 0.5*(1 - ct[16 + j])
    wx[j] = xs[(tq * 4 + j) * 64 + c] * (0.5f * (1.0f - ct[16 + j]));
  }
#pragma unroll
  for (int f = 0; f < NF; ++f) {
    float re = 0.0f, im = 0.0f;
#pragma unroll
    for (int j = 0; j < 16; ++j) {
      re += wx[j] * ct[f * 16 + j];
      im -= wx[j] * st[f * 16 + j];
    }
    out[f] = (_Float16)sqrtf(re * re + im * im);
  }
}

// ---------------------------------------------------------------------------
// Kernel 2: weight repack fp32 [O=512][I=576][K=3] -> fp16 wk[k][o][i]
// ---------------------------------------------------------------------------
__global__ __launch_bounds__(256) void wrepack_kernel(const float* __restrict__ w,
                                                      _Float16* __restrict__ wk) {
  int idx = blockIdx.x * 256 + threadIdx.x;   // o*576 + i
  if (idx >= OCH * ICH) return;
  int o = idx / ICH, i = idx - o * ICH;
  const float* src = w + (size_t)o * (ICH * 3) + i * 3;
#pragma unroll
  for (int k = 0; k < 3; ++k)
    wk[(size_t)k * OCH * ICH + idx] = (_Float16)src[k];
}

// ---------------------------------------------------------------------------
// Kernel 3: conv-as-GEMM.  For each batch b:
//   y[t][o] = sum_{k=0..2} sum_i wk[k][o][i] * m[b][t+k][i]
// 128x128 tile, BK=64 (each K-block has uniform tap k since 576%64==0 -> free
// im2col: B-tile base row shifts by k). 4 waves, each 64(o)x64(t) via 4x4
// mfma 16x16x32. MFMA first operand = t-fragment so D rows = t, cols = o
// -> y stored [b][t][o] (t padded to 1024) for coalesced pool reads.
// grid = (8 t-tiles, 4 o-tiles, 32 batches), block 256.
// ---------------------------------------------------------------------------
#define BM 128
#define BN 128
#define BK 64
#define LDK 72   // LDS row stride in halves: +16B pad -> 2-way bank alias (free)

__global__ __launch_bounds__(256, 2) void conv_gemm_kernel(
    const _Float16* __restrict__ m_ws, const _Float16* __restrict__ wk,
    float* __restrict__ y) {
  const int b = blockIdx.z;
  const int o0 = blockIdx.y * BM;
  const int t0 = blockIdx.x * BN;
  const int tid = threadIdx.x;
  const int wave = tid >> 6, lane = tid & 63;
  const int wm = wave >> 1, wn = wave & 1;       // 2x2 wave grid

  __shared__ _Float16 as[BM * LDK];
  __shared__ _Float16 bs[BN * LDK];

  floatx4 acc[4][4];
#pragma unroll
  for (int mt = 0; mt < 4; ++mt)
#pragma unroll
    for (int nt = 0; nt < 4; ++nt)
      acc[mt][nt] = (floatx4)0.0f;

  const _Float16* mb = m_ws + (size_t)b * T_ROWS * ICH;
  const int frow = lane & 15;          // non-K fragment index
  const int kq = (lane >> 4) * 8;      // K sub-offset per quad

  for (int kb = 0; kb < 27; ++kb) {
    const int ksh = kb / 9;                    // conv tap 0..2
    const int i0 = (kb - ksh * 9) * BK;        // (kb%9)*64
    const _Float16* ag = wk + (size_t)ksh * OCH * ICH + (size_t)o0 * ICH + i0;
    const _Float16* bg = mb + (size_t)(t0 + ksh) * ICH + i0;

#pragma unroll
    for (int it = 0; it < 4; ++it) {
      int e = it * 256 + tid;                  // 0..1023 chunk id
      int row = e >> 3, c8 = (e & 7) * 8;
      *(half8*)(&as[row * LDK + c8]) = *(const half8*)(ag + (size_t)row * ICH + c8);
      *(half8*)(&bs[row * LDK + c8]) = *(const half8*)(bg + (size_t)row * ICH + c8);
    }
    __syncthreads();

#pragma unroll
    for (int kk = 0; kk < BK; kk += 32) {
      half8 af[4], bf[4];
#pragma unroll
      for (int mt = 0; mt < 4; ++mt)
        af[mt] = *(const half8*)(&as[(wm * 64 + mt * 16 + frow) * LDK + kk + kq]);
#pragma unroll
      for (int nt = 0; nt < 4; ++nt)
        bf[nt] = *(const half8*)(&bs[(wn * 64 + nt * 16 + frow) * LDK + kk + kq]);
      // first operand = t-fragment => D row (quad*4+reg) = t, D col (lane&15) = o
#pragma unroll
      for (int mt = 0; mt < 4; ++mt)
#pragma unroll
        for (int nt = 0; nt < 4; ++nt)
          acc[mt][nt] = __builtin_amdgcn_mfma_f32_16x16x32_f16(bf[nt], af[mt],
                                                               acc[mt][nt], 0, 0, 0);
    }
    __syncthreads();
  }

  // epilogue: y[b][t][o], t stride padded to 1024 rows of OCH floats
  const int col = lane & 15, quad = lane >> 4;
  float* yb = y + (((size_t)b << 10)) * OCH;
#pragma unroll
  for (int mt = 0; mt < 4; ++mt) {
    const int o = o0 + wm * 64 + mt * 16 + col;
#pragma unroll
    for (int nt = 0; nt < 4; ++nt) {
      const int tb = t0 + wn * 64 + nt * 16 + quad * 4;
#pragma unroll
      for (int r = 0; r < 4; ++r) {
        yb[(size_t)(tb + r) * OCH + o] = acc[mt][nt][r];
      }
    }
  }
}

// ---------------------------------------------------------------------------
// Kernel 4: adaptive avg pool (overlapping torch bins) + bias.
// out[b][w][o] = bias[o] + mean_{t in [floor(w*1023/128), ceil((w+1)*1023/128))} y[b][t][o]
// y layout [b][t(pad 1024)][o] -> fully coalesced reads along o.
// grid = (128 w, 32 b), block = 512 (o)
// ---------------------------------------------------------------------------
__global__ __launch_bounds__(512) void pool_kernel(const float* __restrict__ y,
                                                   const float* __restrict__ bias,
                                                   float* __restrict__ out) {
  const int b = blockIdx.y, w = blockIdx.x;
  const int o = threadIdx.x;
  const int start = (w * TY) >> 7;
  const int end = ((w + 1) * TY + 127) >> 7;
  const float* yb = y + (((size_t)b << 10)) * OCH;
  float s = 0.0f;
  for (int t = start; t < end; ++t) s += yb[(size_t)t * OCH + o];
  out[((size_t)b * OUTW + w) * OCH + o] = s / (float)(end - start) + bias[o];
}

// ---------------------------------------------------------------------------
extern "C" void kernel_launch(void* const* d_in, const int* in_sizes, int n_in,
                              void* d_out, int out_size, void* d_ws, size_t ws_size,
                              hipStream_t stream) {
  const float* x = (const float*)d_in[0];       // [32, 4096, 64]
  const float* weight = (const float*)d_in[1];  // [512, 576, 3]
  const float* bias = (const float*)d_in[2];    // [512]
  float* out = (float*)d_out;                   // [32, 128, 512]

  char* ws = (char*)d_ws;
  const size_t m_bytes = (size_t)BATCH * T_ROWS * ICH * sizeof(_Float16);  // 38,043,648
  const size_t w_bytes = (size_t)3 * OCH * ICH * sizeof(_Float16);         // 1,769,472
  _Float16* m_ws = (_Float16*)ws;
  _Float16* wk = (_Float16*)(ws + m_bytes);
  float* y = (float*)(ws + m_bytes + w_bytes);  // [32][1024][512] fp32 = 67,108,864

  hipLaunchKernelGGL(stft_kernel, dim3(T_ROWS / 4, BATCH), dim3(256), 0, stream,
                     x, m_ws);
  hipLaunchKernelGGL(wrepack_kernel, dim3((OCH * ICH + 255) / 256), dim3(256), 0,
                     stream, weight, wk);
  hipLaunchKernelGGL(conv_gemm_kernel, dim3(8, 4, BATCH), dim3(256), 0, stream,
                     m_ws, wk, y);
  hipLaunchKernelGGL(pool_kernel, dim3(OUTW, BATCH), dim3(512), 0, stream,
                     y, bias, out);
}

// Round 3
// 189.349 us; speedup vs baseline: 2.2544x; 1.1283x over previous
//
#include <hip/hip_runtime.h>
#include <hip/hip_bf16.h>

// Problem constants
#define BATCH 32
#define LTOT 4096
#define CCH 64
#define NFFT 16
#define HOP 4
#define NF 9            // n_fft/2+1
#define T_FR 1025       // 1 + L/HOP
#define T_ROWS 1032     // padded rows in mag workspace (rows >= 1025 zeroed)
#define ICH 576         // C * NF
#define OCH 512
#define TY 1023         // conv output length
#define OUTW 128

typedef __attribute__((ext_vector_type(8))) _Float16 half8;
typedef __attribute__((ext_vector_type(4))) float floatx4;

// ---------------------------------------------------------------------------
// Kernel 1: STFT magnitude.  x [B, L, C] fp32 -> m_ws [b][t][c*9+f] fp16.
// Direct 16-point DFT with LDS cos/sin tables. Rows t in [1025, T_ROWS) zeroed.
// block = 256 threads = 64 c x 4 t; grid = (T_ROWS/4, B)
// ---------------------------------------------------------------------------
__global__ __launch_bounds__(256) void stft_kernel(const float* __restrict__ x,
                                                   _Float16* __restrict__ m_ws) {
  const int b = blockIdx.y;
  const int t0 = blockIdx.x * 4;
  const int tid = threadIdx.x;

  __shared__ float xs[28 * 64];    // frames for 4 t values: 4*4+12 = 28 rows of x
  __shared__ float ct[9 * 16], st[9 * 16];

  if (tid < 144) {
    int f = tid / 16, j = tid % 16;
    float ang = 3.14159265358979323846f * (float)(f * j) / 8.0f;
    ct[tid] = cosf(ang);
    st[tid] = sinf(ang);
  }

  // stage x rows l0 .. l0+27 with reflect padding
  const int l0 = t0 * HOP - 8;
  const float* xb = x + (size_t)b * LTOT * CCH;
  for (int it = 0; it < 7; ++it) {
    int e = it * 256 + tid;
    int r = e >> 6, c = e & 63;
    int l = l0 + r;
    if (l < 0) l = -l;
    if (l >= LTOT) l = 2 * LTOT - 2 - l;
    xs[r * 64 + c] = xb[(size_t)l * CCH + c];
  }
  __syncthreads();

  const int c = tid & 63, tq = tid >> 6;
  const int t = t0 + tq;
  if (t >= T_ROWS) return;
  _Float16* out = m_ws + ((size_t)b * T_ROWS + t) * ICH + c * NF;
  if (t >= T_FR) {
    for (int f = 0; f < NF; ++f) out[f] = (_Float16)0.0f;
    return;
  }
  float wx[16];
#pragma unroll
  for (int j = 0; j < 16; ++j) {
    // periodic hann: 0.5*(1 - cos(pi*j/8)) == 0.5*(1 - ct[16 + j])
    wx[j] = xs[(tq * 4 + j) * 64 + c] * (0.5f * (1.0f - ct[16 + j]));
  }
#pragma unroll
  for (int f = 0; f < NF; ++f) {
    float re = 0.0f, im = 0.0f;
#pragma unroll
    for (int j = 0; j < 16; ++j) {
      re += wx[j] * ct[f * 16 + j];
      im -= wx[j] * st[f * 16 + j];
    }
    out[f] = (_Float16)sqrtf(re * re + im * im);
  }
}

// ---------------------------------------------------------------------------
// Kernel 2: weight repack fp32 [O=512][I=576][K=3] -> fp16 wk[k][o][i]
// ---------------------------------------------------------------------------
__global__ __launch_bounds__(256) void wrepack_kernel(const float* __restrict__ w,
                                                      _Float16* __restrict__ wk) {
  int idx = blockIdx.x * 256 + threadIdx.x;   // o*576 + i
  if (idx >= OCH * ICH) return;
  int o = idx / ICH, i = idx - o * ICH;
  const float* src = w + (size_t)o * (ICH * 3) + i * 3;
#pragma unroll
  for (int k = 0; k < 3; ++k)
    wk[(size_t)k * OCH * ICH + idx] = (_Float16)src[k];
}

// ---------------------------------------------------------------------------
// Kernel 3: conv-as-GEMM with global_load_lds width=16 staging + XOR swizzle.
//   y[t][o] = sum_{k=0..2} sum_i wk[k][o][i] * m[b][t+k][i]
// 128x128 tile, BK=64. LDS rows are unpadded 128 B (required: DMA dest is
// wave-uniform base + lane*16). Chunk c (16 B) of row r lives at LDS slot
// c ^ (r & 7); the swizzle is applied to the *global source* per lane during
// staging and to the chunk index on fragment reads -> 2-way max bank alias
// (free, m136), zero conflicts.
// grid = (8 t-tiles, 4 o-tiles, 32 batches), block 256 (4 waves, 2x2).
// ---------------------------------------------------------------------------
#define BM 128
#define BN 128
#define BK 64

__device__ __forceinline__ void async_copy16(const _Float16* g, _Float16* l) {
  __builtin_amdgcn_global_load_lds(
      (const __attribute__((address_space(1))) unsigned int*)g,
      (__attribute__((address_space(3))) unsigned int*)l, 16, 0, 0);
}

__global__ __launch_bounds__(256, 4) void conv_gemm_kernel(
    const _Float16* __restrict__ m_ws, const _Float16* __restrict__ wk,
    float* __restrict__ y) {
  const int b = blockIdx.z;
  const int o0 = blockIdx.y * BM;
  const int t0 = blockIdx.x * BN;
  const int tid = threadIdx.x;
  const int wave = tid >> 6, lane = tid & 63;
  const int wm = wave >> 1, wn = wave & 1;       // 2x2 wave grid

  __shared__ _Float16 as[BM * BK];   // 16 KB, rows of 64 halves (128 B)
  __shared__ _Float16 bs[BN * BK];   // 16 KB

  floatx4 acc[4][4];
#pragma unroll
  for (int mt = 0; mt < 4; ++mt)
#pragma unroll
    for (int nt = 0; nt < 4; ++nt)
      acc[mt][nt] = (floatx4)0.0f;

  const _Float16* mb = m_ws + (size_t)b * T_ROWS * ICH;
  const int frow = lane & 15;          // non-K fragment index
  const int quad = lane >> 4;
  const int l7 = lane & 7;

  // staging geometry: one global_load_lds covers 8 rows (64 lanes x 16 B).
  // lane -> row_in_seg = lane>>3, src chunk = (lane&7) ^ (lane>>3)  (swizzle)
  const int srow = lane >> 3;                  // 0..7
  const int schunk = l7 ^ srow;                // swizzled source 16B-chunk
  // per-lane half offsets within a row-block
  const int ssrc_off = srow * ICH + schunk * 8;

  for (int kb = 0; kb < 27; ++kb) {
    const int ksh = kb / 9;                    // conv tap 0..2
    const int i0 = (kb - ksh * 9) * BK;        // (kb%9)*64
    const _Float16* ag = wk + (size_t)ksh * OCH * ICH + (size_t)o0 * ICH + i0;
    const _Float16* bg = mb + (size_t)(t0 + ksh) * ICH + i0;

#pragma unroll
    for (int it = 0; it < 4; ++it) {
      const int seg = wave * 4 + it;           // 0..15, 8 rows each
      async_copy16(ag + (size_t)(seg * 8) * ICH + ssrc_off, &as[seg * 512]);
      async_copy16(bg + (size_t)(seg * 8) * ICH + ssrc_off, &bs[seg * 512]);
    }
    __syncthreads();   // drains vmcnt (global_load_lds) + barrier

#pragma unroll
    for (int kk2 = 0; kk2 < 2; ++kk2) {
      const int jj = kk2 * 4 + quad;           // K 16B-chunk index 0..7
      const int coff = ((jj ^ l7) << 3);       // swizzled half offset in row
      half8 af[4], bf[4];
#pragma unroll
      for (int mt = 0; mt < 4; ++mt)
        af[mt] = *(const half8*)(&as[(wm * 64 + mt * 16 + frow) * 64 + coff]);
#pragma unroll
      for (int nt = 0; nt < 4; ++nt)
        bf[nt] = *(const half8*)(&bs[(wn * 64 + nt * 16 + frow) * 64 + coff]);
      // first operand = t-fragment => D row (quad*4+reg) = t, D col (lane&15) = o
#pragma unroll
      for (int mt = 0; mt < 4; ++mt)
#pragma unroll
        for (int nt = 0; nt < 4; ++nt)
          acc[mt][nt] = __builtin_amdgcn_mfma_f32_16x16x32_f16(bf[nt], af[mt],
                                                               acc[mt][nt], 0, 0, 0);
    }
    __syncthreads();
  }

  // epilogue: y[b][t][o], t stride padded to 1024 rows of OCH floats
  const int col = lane & 15;
  float* yb = y + (((size_t)b << 10)) * OCH;
#pragma unroll
  for (int mt = 0; mt < 4; ++mt) {
    const int o = o0 + wm * 64 + mt * 16 + col;
#pragma unroll
    for (int nt = 0; nt < 4; ++nt) {
      const int tb = t0 + wn * 64 + nt * 16 + quad * 4;
#pragma unroll
      for (int r = 0; r < 4; ++r) {
        yb[(size_t)(tb + r) * OCH + o] = acc[mt][nt][r];
      }
    }
  }
}

// ---------------------------------------------------------------------------
// Kernel 4: adaptive avg pool (overlapping torch bins) + bias.
// out[b][w][o] = bias[o] + mean_{t in [floor(w*1023/128), ceil((w+1)*1023/128))} y[b][t][o]
// y layout [b][t(pad 1024)][o] -> fully coalesced reads along o.
// grid = (128 w, 32 b), block = 512 (o)
// ---------------------------------------------------------------------------
__global__ __launch_bounds__(512) void pool_kernel(const float* __restrict__ y,
                                                   const float* __restrict__ bias,
                                                   float* __restrict__ out) {
  const int b = blockIdx.y, w = blockIdx.x;
  const int o = threadIdx.x;
  const int start = (w * TY) >> 7;
  const int end = ((w + 1) * TY + 127) >> 7;
  const float* yb = y + (((size_t)b << 10)) * OCH;
  float s = 0.0f;
  for (int t = start; t < end; ++t) s += yb[(size_t)t * OCH + o];
  out[((size_t)b * OUTW + w) * OCH + o] = s / (float)(end - start) + bias[o];
}

// ---------------------------------------------------------------------------
extern "C" void kernel_launch(void* const* d_in, const int* in_sizes, int n_in,
                              void* d_out, int out_size, void* d_ws, size_t ws_size,
                              hipStream_t stream) {
  const float* x = (const float*)d_in[0];       // [32, 4096, 64]
  const float* weight = (const float*)d_in[1];  // [512, 576, 3]
  const float* bias = (const float*)d_in[2];    // [512]
  float* out = (float*)d_out;                   // [32, 128, 512]

  char* ws = (char*)d_ws;
  const size_t m_bytes = (size_t)BATCH * T_ROWS * ICH * sizeof(_Float16);  // 38,043,648
  const size_t w_bytes = (size_t)3 * OCH * ICH * sizeof(_Float16);         // 1,769,472
  _Float16* m_ws = (_Float16*)ws;
  _Float16* wk = (_Float16*)(ws + m_bytes);
  float* y = (float*)(ws + m_bytes + w_bytes);  // [32][1024][512] fp32 = 67,108,864

  hipLaunchKernelGGL(stft_kernel, dim3(T_ROWS / 4, BATCH), dim3(256), 0, stream,
                     x, m_ws);
  hipLaunchKernelGGL(wrepack_kernel, dim3((OCH * ICH + 255) / 256), dim3(256), 0,
                     stream, weight, wk);
  hipLaunchKernelGGL(conv_gemm_kernel, dim3(8, 4, BATCH), dim3(256), 0, stream,
                     m_ws, wk, y);
  hipLaunchKernelGGL(pool_kernel, dim3(OUTW, BATCH), dim3(512), 0, stream,
                     y, bias, out);
}

// Round 4
// 183.005 us; speedup vs baseline: 2.3326x; 1.0347x over previous
//
#include <hip/hip_runtime.h>
#include <hip/hip_bf16.h>

// Problem constants
#define BATCH 32
#define LTOT 4096
#define CCH 64
#define NFFT 16
#define HOP 4
#define NF 9            // n_fft/2+1
#define T_FR 1025       // 1 + L/HOP
#define T_ROWS 1032     // padded rows in mag workspace (rows >= 1025 zeroed)
#define ICH 576         // C * NF
#define OCH 512
#define TY 1023         // conv output length
#define OUTW 128

typedef __attribute__((ext_vector_type(8))) _Float16 half8;
typedef __attribute__((ext_vector_type(4))) float floatx4;

// cos(n*pi/8), sin(n*pi/8) for n = 0..15 — compile-time twiddles; all DFT
// coefficients are C16/S16[(f*j)&15]. Full unroll -> fp32 immediates in v_fma.
__device__ constexpr float C16[16] = {
    1.0f,  0.923879533f,  0.707106781f,  0.382683432f,  0.0f, -0.382683432f,
   -0.707106781f, -0.923879533f, -1.0f, -0.923879533f, -0.707106781f,
   -0.382683432f,  0.0f,  0.382683432f,  0.707106781f,  0.923879533f};
__device__ constexpr float S16[16] = {
    0.0f,  0.382683432f,  0.707106781f,  0.923879533f,  1.0f,  0.923879533f,
    0.707106781f,  0.382683432f,  0.0f, -0.382683432f, -0.707106781f,
   -0.923879533f, -1.0f, -0.923879533f, -0.707106781f, -0.382683432f};

// ---------------------------------------------------------------------------
// Kernel 1: STFT magnitude.  x [B, L, C] fp32 -> m_ws [b][t][f*64+c] fp16.
// NOTE the i-axis permutation (f-major): legal because the conv sums over i
// and wrepack applies the SAME permutation. Makes the 9 stores per thread
// lane-contiguous (128 B segments) instead of scattered 2 B.
// Twiddles are compile-time constants (zero LDS table reads).
// block = 256 threads = 64 c x 4 t; grid = (T_ROWS/4, B)
// ---------------------------------------------------------------------------
__global__ __launch_bounds__(256) void stft_kernel(const float* __restrict__ x,
                                                   _Float16* __restrict__ m_ws) {
  const int b = blockIdx.y;
  const int t0 = blockIdx.x * 4;
  const int tid = threadIdx.x;

  __shared__ float xs[28 * 64];    // frames for 4 t values: 4*4+12 = 28 rows of x

  // stage x rows l0 .. l0+27 with reflect padding
  const int l0 = t0 * HOP - 8;
  const float* xb = x + (size_t)b * LTOT * CCH;
#pragma unroll
  for (int it = 0; it < 7; ++it) {
    int e = it * 256 + tid;
    int r = e >> 6, c = e & 63;
    int l = l0 + r;
    if (l < 0) l = -l;
    if (l >= LTOT) l = 2 * LTOT - 2 - l;
    xs[r * 64 + c] = xb[(size_t)l * CCH + c];
  }
  __syncthreads();

  const int c = tid & 63, tq = tid >> 6;
  const int t = t0 + tq;
  if (t >= T_ROWS) return;
  _Float16* out = m_ws + ((size_t)b * T_ROWS + t) * ICH + c;  // + f*64 per bin
  if (t >= T_FR) {
#pragma unroll
    for (int f = 0; f < NF; ++f) out[f * 64] = (_Float16)0.0f;
    return;
  }
  float wx[16];
#pragma unroll
  for (int j = 0; j < 16; ++j) {
    // periodic hann: 0.5*(1 - cos(pi*j/8)) — compile-time constant
    wx[j] = xs[(tq * 4 + j) * 64 + c] * (0.5f * (1.0f - C16[j]));
  }
#pragma unroll
  for (int f = 0; f < NF; ++f) {
    float re = 0.0f, im = 0.0f;
#pragma unroll
    for (int j = 0; j < 16; ++j) {
      re += wx[j] * C16[(f * j) & 15];
      im -= wx[j] * S16[(f * j) & 15];
    }
    out[f * 64] = (_Float16)sqrtf(re * re + im * im);
  }
}

// ---------------------------------------------------------------------------
// Kernel 2: weight repack fp32 [O=512][I=576][K=3] -> fp16 wk[k][o][f*64+c]
// (same i-axis permutation as stft: src i = c*9+f -> dst f*64+c)
// ---------------------------------------------------------------------------
__global__ __launch_bounds__(256) void wrepack_kernel(const float* __restrict__ w,
                                                      _Float16* __restrict__ wk) {
  int idx = blockIdx.x * 256 + threadIdx.x;   // o*576 + i
  if (idx >= OCH * ICH) return;
  int o = idx / ICH, i = idx - o * ICH;
  int c = i / 9, f = i - c * 9;
  const float* src = w + (size_t)o * (ICH * 3) + i * 3;
  const size_t dst = (size_t)o * ICH + f * 64 + c;
#pragma unroll
  for (int k = 0; k < 3; ++k)
    wk[(size_t)k * OCH * ICH + dst] = (_Float16)src[k];
}

// ---------------------------------------------------------------------------
// Kernel 3: conv-as-GEMM with global_load_lds width=16 staging + XOR swizzle.
//   y[t][o] = sum_{k=0..2} sum_i wk[k][o][i] * m[b][t+k][i]
// 128x128 tile, BK=64. LDS rows are unpadded 128 B (required: DMA dest is
// wave-uniform base + lane*16). Chunk c (16 B) of row r lives at LDS slot
// c ^ (r & 7); swizzle applied on global source during staging and on chunk
// index at fragment reads -> zero bank conflicts (verified R3).
// grid = (8 t-tiles, 4 o-tiles, 32 batches), block 256 (4 waves, 2x2).
// ---------------------------------------------------------------------------
#define BM 128
#define BN 128
#define BK 64

__device__ __forceinline__ void async_copy16(const _Float16* g, _Float16* l) {
  __builtin_amdgcn_global_load_lds(
      (const __attribute__((address_space(1))) unsigned int*)g,
      (__attribute__((address_space(3))) unsigned int*)l, 16, 0, 0);
}

__global__ __launch_bounds__(256, 4) void conv_gemm_kernel(
    const _Float16* __restrict__ m_ws, const _Float16* __restrict__ wk,
    float* __restrict__ y) {
  const int b = blockIdx.z;
  const int o0 = blockIdx.y * BM;
  const int t0 = blockIdx.x * BN;
  const int tid = threadIdx.x;
  const int wave = tid >> 6, lane = tid & 63;
  const int wm = wave >> 1, wn = wave & 1;       // 2x2 wave grid

  __shared__ _Float16 as[BM * BK];   // 16 KB, rows of 64 halves (128 B)
  __shared__ _Float16 bs[BN * BK];   // 16 KB

  floatx4 acc[4][4];
#pragma unroll
  for (int mt = 0; mt < 4; ++mt)
#pragma unroll
    for (int nt = 0; nt < 4; ++nt)
      acc[mt][nt] = (floatx4)0.0f;

  const _Float16* mb = m_ws + (size_t)b * T_ROWS * ICH;
  const int frow = lane & 15;          // non-K fragment index
  const int quad = lane >> 4;
  const int l7 = lane & 7;

  // staging geometry: one global_load_lds covers 8 rows (64 lanes x 16 B).
  const int srow = lane >> 3;                  // 0..7
  const int schunk = l7 ^ srow;                // swizzled source 16B-chunk
  const int ssrc_off = srow * ICH + schunk * 8;

  for (int kb = 0; kb < 27; ++kb) {
    const int ksh = kb / 9;                    // conv tap 0..2
    const int i0 = (kb - ksh * 9) * BK;        // (kb%9)*64
    const _Float16* ag = wk + (size_t)ksh * OCH * ICH + (size_t)o0 * ICH + i0;
    const _Float16* bg = mb + (size_t)(t0 + ksh) * ICH + i0;

#pragma unroll
    for (int it = 0; it < 4; ++it) {
      const int seg = wave * 4 + it;           // 0..15, 8 rows each
      async_copy16(ag + (size_t)(seg * 8) * ICH + ssrc_off, &as[seg * 512]);
      async_copy16(bg + (size_t)(seg * 8) * ICH + ssrc_off, &bs[seg * 512]);
    }
    __syncthreads();   // drains vmcnt (global_load_lds) + barrier

#pragma unroll
    for (int kk2 = 0; kk2 < 2; ++kk2) {
      const int jj = kk2 * 4 + quad;           // K 16B-chunk index 0..7
      const int coff = ((jj ^ l7) << 3);       // swizzled half offset in row
      half8 af[4], bf[4];
#pragma unroll
      for (int mt = 0; mt < 4; ++mt)
        af[mt] = *(const half8*)(&as[(wm * 64 + mt * 16 + frow) * 64 + coff]);
#pragma unroll
      for (int nt = 0; nt < 4; ++nt)
        bf[nt] = *(const half8*)(&bs[(wn * 64 + nt * 16 + frow) * 64 + coff]);
      // first operand = t-fragment => D row (quad*4+reg) = t, D col (lane&15) = o
#pragma unroll
      for (int mt = 0; mt < 4; ++mt)
#pragma unroll
        for (int nt = 0; nt < 4; ++nt)
          acc[mt][nt] = __builtin_amdgcn_mfma_f32_16x16x32_f16(bf[nt], af[mt],
                                                               acc[mt][nt], 0, 0, 0);
    }
    __syncthreads();
  }

  // epilogue: y[b][t][o], t stride padded to 1024 rows of OCH floats
  const int col = lane & 15;
  float* yb = y + (((size_t)b << 10)) * OCH;
#pragma unroll
  for (int mt = 0; mt < 4; ++mt) {
    const int o = o0 + wm * 64 + mt * 16 + col;
#pragma unroll
    for (int nt = 0; nt < 4; ++nt) {
      const int tb = t0 + wn * 64 + nt * 16 + quad * 4;
#pragma unroll
      for (int r = 0; r < 4; ++r) {
        yb[(size_t)(tb + r) * OCH + o] = acc[mt][nt][r];
      }
    }
  }
}

// ---------------------------------------------------------------------------
// Kernel 4: adaptive avg pool (overlapping torch bins) + bias.
// out[b][w][o] = bias[o] + mean_{t in [floor(w*1023/128), ceil((w+1)*1023/128))} y[b][t][o]
// y layout [b][t(pad 1024)][o] -> fully coalesced reads along o.
// grid = (128 w, 32 b), block = 512 (o)
// ---------------------------------------------------------------------------
__global__ __launch_bounds__(512) void pool_kernel(const float* __restrict__ y,
                                                   const float* __restrict__ bias,
                                                   float* __restrict__ out) {
  const int b = blockIdx.y, w = blockIdx.x;
  const int o = threadIdx.x;
  const int start = (w * TY) >> 7;
  const int end = ((w + 1) * TY + 127) >> 7;
  const float* yb = y + (((size_t)b << 10)) * OCH;
  float s = 0.0f;
  for (int t = start; t < end; ++t) s += yb[(size_t)t * OCH + o];
  out[((size_t)b * OUTW + w) * OCH + o] = s / (float)(end - start) + bias[o];
}

// ---------------------------------------------------------------------------
extern "C" void kernel_launch(void* const* d_in, const int* in_sizes, int n_in,
                              void* d_out, int out_size, void* d_ws, size_t ws_size,
                              hipStream_t stream) {
  const float* x = (const float*)d_in[0];       // [32, 4096, 64]
  const float* weight = (const float*)d_in[1];  // [512, 576, 3]
  const float* bias = (const float*)d_in[2];    // [512]
  float* out = (float*)d_out;                   // [32, 128, 512]

  char* ws = (char*)d_ws;
  const size_t m_bytes = (size_t)BATCH * T_ROWS * ICH * sizeof(_Float16);  // 38,043,648
  const size_t w_bytes = (size_t)3 * OCH * ICH * sizeof(_Float16);         // 1,769,472
  _Float16* m_ws = (_Float16*)ws;
  _Float16* wk = (_Float16*)(ws + m_bytes);
  float* y = (float*)(ws + m_bytes + w_bytes);  // [32][1024][512] fp32 = 67,108,864

  hipLaunchKernelGGL(stft_kernel, dim3(T_ROWS / 4, BATCH), dim3(256), 0, stream,
                     x, m_ws);
  hipLaunchKernelGGL(wrepack_kernel, dim3((OCH * ICH + 255) / 256), dim3(256), 0,
                     stream, weight, wk);
  hipLaunchKernelGGL(conv_gemm_kernel, dim3(8, 4, BATCH), dim3(256), 0, stream,
                     m_ws, wk, y);
  hipLaunchKernelGGL(pool_kernel, dim3(OUTW, BATCH), dim3(512), 0, stream,
                     y, bias, out);
}